// Round 4
// baseline (680.296 us; speedup 1.0000x reference)
//
#include <hip/hip_runtime.h>

#define B_    64
#define N_    100
#define D_    32
#define F0    96
#define F1    160
#define F2    192
#define HID   256
#define FOUT  32

typedef unsigned short u16;
typedef unsigned int   u32;
typedef u16   u16x8 __attribute__((ext_vector_type(8)));
typedef __bf16 bf16x8 __attribute__((ext_vector_type(8)));
typedef __bf16 bf16x2 __attribute__((ext_vector_type(2)));
typedef float  fx4   __attribute__((ext_vector_type(4)));

__device__ __forceinline__ u16 f2bfu(float f) {
    u32 u = __float_as_uint(f);
    u += 0x7fffu + ((u >> 16) & 1u);   // RNE
    return (u16)(u >> 16);
}
// pack two floats -> two bf16 in one u32 (low = first arg)
#if __has_builtin(__builtin_amdgcn_cvt_pk_bf16_f32)
__device__ __forceinline__ u32 pk2(float a, float b) {
    bf16x2 t = __builtin_amdgcn_cvt_pk_bf16_f32(a, b);
    return __builtin_bit_cast(u32, t);
}
#else
__device__ __forceinline__ u32 pk2(float a, float b) {
    return (u32)f2bfu(a) | ((u32)f2bfu(b) << 16);
}
#endif
__device__ __forceinline__ float lrelu(float v) { return fmaxf(v, 0.2f * v); }

__device__ __forceinline__ bf16x8 fragLds(const u16* p) {
    return __builtin_bit_cast(bf16x8, *(const u16x8*)p);
}
__device__ __forceinline__ bf16x8 fragGbl(const u16* __restrict__ p) {
    return __builtin_bit_cast(bf16x8, *(const u16x8*)p);
}
#define MFMA(a, b, c) __builtin_amdgcn_mfma_f32_16x16x32_bf16((a), (b), (c), 0, 0, 0)

// ---- ws layout (bytes) ----
#define OFF_P     0u
#define OFF_V     2457600u     // 6400*96*4
#define OFF_AGG   4915200u     // + 6400*96*4
#define OFF_PACK  7372800u     // + 6400*192*2
// packed weights (u16 element offsets within pack region)
// NOTE: A-frag pack of W^T == B-frag pack of W, so layout is identical to R3.
#define PK_W1     0            // 96x160  -> 15360
#define PK_W2     15360        // 160x192 -> 30720
#define PK_N0     46080        // 224x256 -> 57344
#define PK_N1     103424       // 256x256 -> 65536
#define PK_N2     168960       // 256x32  -> 8192
#define PK_TOTAL  177152

#define PV_BLOCKS 2400         // 6400*192 / 512
#define PACK_BLOCKS 346        // 177152 / 512

// ============================ prep ============================
__global__ __launch_bounds__(512) void prep_kernel(
    const float* __restrict__ x,
    const float* __restrict__ few0, const float* __restrict__ feb0,
    const float* __restrict__ few1, const float* __restrict__ few2,
    const float* __restrict__ fnw0, const float* __restrict__ fnw1,
    const float* __restrict__ fnw2,
    float* __restrict__ P, float* __restrict__ V, u16* __restrict__ wpack)
{
    const int blk = blockIdx.x, tid = threadIdx.x;
    if (blk < PV_BLOCKS) {
        int o = blk * 512 + tid;           // < 6400*192
        int r = o / 192, h = o - r * 192;
        const float* xr = x + r * D_;
        if (h < F0) {
            float acc = feb0[h];
            #pragma unroll
            for (int d = 0; d < D_; ++d) acc = fmaf(xr[d], few0[d * F0 + h], acc);
            P[r * F0 + h] = acc;
        } else {
            int k = h - F0;
            float acc = 0.f;
            #pragma unroll
            for (int d = 0; d < D_; ++d) acc = fmaf(xr[d], few0[(D_ + d) * F0 + k], acc);
            V[r * F0 + k] = acc;
        }
    } else {
        int p = (blk - PV_BLOCKS) * 512 + tid;   // < 177152
        const float* src; int start, Ncols, NT;
        if (p < PK_W2)      { start = PK_W1; src = few1; Ncols = F1;   NT = 10; }
        else if (p < PK_N0) { start = PK_W2; src = few2; Ncols = F2;   NT = 12; }
        else if (p < PK_N1) { start = PK_N0; src = fnw0; Ncols = HID;  NT = 16; }
        else if (p < PK_N2) { start = PK_N1; src = fnw1; Ncols = HID;  NT = 16; }
        else                { start = PK_N2; src = fnw2; Ncols = FOUT; NT = 2;  }
        int local = p - start;
        int j = local & 7, lane = (local >> 3) & 63, rest = local >> 9;
        int nt = rest % NT, kt = rest / NT;
        int n = 16 * nt + (lane & 15);
        int k = 32 * kt + 8 * (lane >> 4) + j;
        wpack[p] = f2bfu(src[k * Ncols + n]);
    }
}

// ============================ edge ============================
// one block per (b,i). Transposed MFMA: D = W^T (A-op) x Act^T (B-op).
// C rows = output features -> epilogue writes 4 consecutive k of next layer's
// B-fragment with one ds_write_b64.
__global__ __launch_bounds__(512, 4) void edge_kernel(
    const float* __restrict__ P, const float* __restrict__ V,
    const u16* __restrict__ W1p, const u16* __restrict__ W2p,
    const float* __restrict__ feb1, const float* __restrict__ feb2,
    u16* __restrict__ agg)
{
    const int i = blockIdx.x, b = blockIdx.y;
    const int tid = threadIdx.x, ld = tid & 63, wv = tid >> 6;
    const int c = ld & 15, Q = ld >> 4;
    const int row = b * N_ + i;

    __shared__ __align__(16) u16  sB0[3 * 7 * 64 * 8];   // 21504 B: A0^T B-pack [mt][kt][lane][j]
    __shared__ __align__(16) u16  sB1[5 * 7 * 64 * 8];   // 35840 B: A1^T B-pack
    __shared__ __align__(16) float sP[F0];               //   384 B
    __shared__ __align__(16) float sAggP[2 * F2];        //  1536 B

    if (tid < 24) ((float4*)sP)[tid] = ((const float4*)(P + (size_t)row * F0))[tid];

    // ---- resident W1^T A-fragments (issued early to hide L2 latency) ----
    const int wf = wv >> 2;            // 0..1 : f-tile group (5 tiles each)
    const int wm = wv & 3;             // 0..3 : m-tile group
    const int ftb = wf * 5;
    bf16x8 aw1[5][3];
    #pragma unroll
    for (int t = 0; t < 5; ++t)
        #pragma unroll
        for (int kt = 0; kt < 3; ++kt)
            aw1[t][kt] = fragGbl(W1p + (size_t)((kt * 10 + ftb + t) * 64 + ld) * 8);

    __syncthreads();   // sP ready

    // ---- build A0^T in B-pack layout: elem(k, m) ----
    // octet o = (mt*3+kt)*64 + lane ; m = 16mt + (lane&15); kb = 32kt + 8*(lane>>4)
    {
        const float* Vb = V + (size_t)b * (N_ * F0);
        #pragma unroll
        for (int s = 0; s < 3; ++s) {
            int o = tid + 512 * s;
            if (o < 1344) {
                int mt = o / 192;
                int rem = o - mt * 192;
                int kt = rem >> 6, lane = rem & 63;
                int m = 16 * mt + (lane & 15);
                int kb = 32 * kt + 8 * (lane >> 4);
                const float* vp = Vb + m * F0 + kb;   // pad rows read garbage (finite) - masked at agg
                float4 va = *(const float4*)vp;
                float4 vb = *(const float4*)(vp + 4);
                float4 pa = *(const float4*)&sP[kb];
                float4 pb = *(const float4*)&sP[kb + 4];
                uint4 w;
                w.x = pk2(lrelu(pa.x + va.x), lrelu(pa.y + va.y));
                w.y = pk2(lrelu(pa.z + va.z), lrelu(pa.w + va.w));
                w.z = pk2(lrelu(pb.x + vb.x), lrelu(pb.y + vb.y));
                w.w = pk2(lrelu(pb.z + vb.z), lrelu(pb.w + vb.w));
                *(uint4*)&sB0[o * 8] = w;
            }
        }
    }
    __syncthreads();

    // ---- layer 1 (transposed): D1[f][m], f in wave's 5 f-tiles, m in wave's m-tiles ----
    {
        const int nmi = (wm == 3) ? 1 : 2;
        for (int mi = 0; mi < nmi; ++mi) {
            int mt = wm + 4 * mi;
            bf16x8 b0[3];
            #pragma unroll
            for (int kt = 0; kt < 3; ++kt)
                b0[kt] = fragLds(sB0 + ((mt * 3 + kt) * 64 + ld) * 8);
            fx4 acc[5];
            #pragma unroll
            for (int t = 0; t < 5; ++t) acc[t] = (fx4){0.f, 0.f, 0.f, 0.f};
            #pragma unroll
            for (int kt = 0; kt < 3; ++kt)
                #pragma unroll
                for (int t = 0; t < 5; ++t)
                    acc[t] = MFMA(aw1[t][kt], b0[kt], acc[t]);
            // epilogue: rows f = 16*(ftb+t) + 4Q + r ; cols m = 16mt + c
            #pragma unroll
            for (int t = 0; t < 5; ++t) {
                int f0 = 16 * (ftb + t) + 4 * Q;
                float4 bias = *(const float4*)(feb1 + f0);
                u32 lo = pk2(lrelu(acc[t][0] + bias.x), lrelu(acc[t][1] + bias.y));
                u32 hi = pk2(lrelu(acc[t][2] + bias.z), lrelu(acc[t][3] + bias.w));
                int kt2 = f0 >> 5, o8 = (f0 >> 3) & 3, j0 = f0 & 7;
                int lane2 = c + 16 * o8;
                *(uint2*)&sB1[((mt * 5 + kt2) * 64 + lane2) * 8 + j0] = (uint2){lo, hi};
            }
        }
    }
    __syncthreads();

    // ---- layer 2 (transposed) + fused aggregation over m ----
    {
        const int wf2 = wv >> 1;       // 0..3 : f2-tiles {wf2, wf2+4, wf2+8}
        const int wm2 = wv & 1;        // 0..1 : m-tiles wm2, wm2+2, ...
        const int nmi = 4 - wm2;       // wm2=0 -> {0,2,4,6}; wm2=1 -> {1,3,5}
        fx4 acc[4][3];
        #pragma unroll
        for (int mi = 0; mi < 4; ++mi)
            #pragma unroll
            for (int t = 0; t < 3; ++t) acc[mi][t] = (fx4){0.f, 0.f, 0.f, 0.f};

        // k-slabs of 2 to bound VGPR (A-frags streamed per slab)
        #pragma unroll
        for (int slab = 0; slab < 3; ++slab) {
            const int k0 = slab * 2, nk = (slab == 2) ? 1 : 2;
            bf16x8 aw2[3][2];
            #pragma unroll
            for (int t = 0; t < 3; ++t)
                #pragma unroll
                for (int kk = 0; kk < 2; ++kk)
                    if (kk < nk)
                        aw2[t][kk] = fragGbl(W2p + (size_t)(((k0 + kk) * 12 + wf2 + 4 * t) * 64 + ld) * 8);
            for (int mi = 0; mi < nmi; ++mi) {
                int mt = wm2 + 2 * mi;
                #pragma unroll
                for (int kk = 0; kk < 2; ++kk) {
                    if (kk < nk) {
                        bf16x8 b1 = fragLds(sB1 + ((mt * 5 + k0 + kk) * 64 + ld) * 8);
                        #pragma unroll
                        for (int t = 0; t < 3; ++t)
                            acc[mi][t] = MFMA(aw2[t][kk], b1, acc[mi][t]);
                    }
                }
            }
        }
        // epilogue: bias + lrelu + accumulate over m (mask pad m>=100 on mt==6)
        float ag[3][4];
        #pragma unroll
        for (int t = 0; t < 3; ++t)
            #pragma unroll
            for (int r = 0; r < 4; ++r) ag[t][r] = 0.f;
        #pragma unroll
        for (int t = 0; t < 3; ++t) {
            int f0 = 16 * (wf2 + 4 * t) + 4 * Q;
            float4 bias = *(const float4*)(feb2 + f0);
            for (int mi = 0; mi < nmi; ++mi) {
                int mt = wm2 + 2 * mi;
                #pragma unroll
                for (int r = 0; r < 4; ++r) {
                    float bb = (r == 0) ? bias.x : (r == 1) ? bias.y : (r == 2) ? bias.z : bias.w;
                    float val = lrelu(acc[mi][t][r] + bb);
                    if (mt == 6 && c >= 4) val = 0.f;   // pad m
                    ag[t][r] += val;
                }
            }
        }
        // reduce over the 16 m-lanes (c)
        #pragma unroll
        for (int t = 0; t < 3; ++t)
            #pragma unroll
            for (int r = 0; r < 4; ++r) {
                float v = ag[t][r];
                v += __shfl_xor(v, 1);
                v += __shfl_xor(v, 2);
                v += __shfl_xor(v, 4);
                v += __shfl_xor(v, 8);
                ag[t][r] = v;
            }
        if (c == 0) {
            #pragma unroll
            for (int t = 0; t < 3; ++t)
                #pragma unroll
                for (int r = 0; r < 4; ++r)
                    sAggP[wm2 * F2 + 16 * (wf2 + 4 * t) + 4 * Q + r] = ag[t][r];
        }
    }
    __syncthreads();

    if (tid < F2)
        agg[(size_t)row * F2 + tid] = f2bfu(sAggP[tid] + sAggP[F2 + tid]);
}

// ============================ node ============================
// 400 blocks x 16 rows, 512 threads (8 waves = 8 n-groups)
__global__ __launch_bounds__(512, 4) void node_kernel(
    const u16* __restrict__ agg, const float* __restrict__ x,
    const u16* __restrict__ n0p, const u16* __restrict__ n1p,
    const u16* __restrict__ n2p,
    const float* __restrict__ fnb0, const float* __restrict__ fnb1,
    const float* __restrict__ fnb2,
    float* __restrict__ out)
{
    const int blk = blockIdx.x;
    const int tid = threadIdx.x, ld = tid & 63, wv = tid >> 6;
    const int c = ld & 15, Q = ld >> 4;

    __shared__ __align__(16) u16 sH0p[7 * 512];   //  7168 B
    __shared__ __align__(16) u16 sH1p[8 * 512];   //  8192 B
    __shared__ __align__(16) u16 sH2p[8 * 512];   //  8192 B

    // ---- stage H0 = [agg | x] in A-pack layout (16 rows) ----
    if (tid < 448) {
        int kt = tid >> 6, lane = tid & 63;
        int m = lane & 15;
        int kb = 32 * kt + 8 * (lane >> 4);
        int g = 16 * blk + m;
        uint4 w;
        if (kb < F2) {
            w = *(const uint4*)(agg + (size_t)g * F2 + kb);
        } else {
            const float* xp = x + (size_t)g * D_ + (kb - F2);
            float4 a = *(const float4*)xp;
            float4 bb = *(const float4*)(xp + 4);
            w.x = pk2(a.x, a.y);  w.y = pk2(a.z, a.w);
            w.z = pk2(bb.x, bb.y); w.w = pk2(bb.z, bb.w);
        }
        *(uint4*)&sH0p[tid * 8] = w;
    }
    __syncthreads();

    // ---- node layer 0: K=224, N=256 ; wave handles nt = wv, wv+8 ----
    {
        fx4 acc[2];
        #pragma unroll
        for (int t = 0; t < 2; ++t) acc[t] = (fx4){0.f, 0.f, 0.f, 0.f};
        for (int kt = 0; kt < 7; ++kt) {
            bf16x8 a = fragLds(sH0p + (kt * 64 + ld) * 8);
            #pragma unroll
            for (int t = 0; t < 2; ++t) {
                bf16x8 bw = fragGbl(n0p + (size_t)((kt * 16 + wv + 8 * t) * 64 + ld) * 8);
                acc[t] = MFMA(a, bw, acc[t]);
            }
        }
        #pragma unroll
        for (int t = 0; t < 2; ++t) {
            int f = 16 * (wv + 8 * t) + c;
            float bias = fnb0[f];
            int kt2 = f >> 5, o8 = (f >> 3) & 3, j2 = f & 7;
            #pragma unroll
            for (int r = 0; r < 4; ++r) {
                float val = lrelu(acc[t][r] + bias);
                sH1p[((kt2) * 64 + (4 * Q + r) + 16 * o8) * 8 + j2] = f2bfu(val);
            }
        }
    }
    __syncthreads();

    // ---- node layer 1: K=256, N=256 ----
    {
        fx4 acc[2];
        #pragma unroll
        for (int t = 0; t < 2; ++t) acc[t] = (fx4){0.f, 0.f, 0.f, 0.f};
        for (int kt = 0; kt < 8; ++kt) {
            bf16x8 a = fragLds(sH1p + (kt * 64 + ld) * 8);
            #pragma unroll
            for (int t = 0; t < 2; ++t) {
                bf16x8 bw = fragGbl(n1p + (size_t)((kt * 16 + wv + 8 * t) * 64 + ld) * 8);
                acc[t] = MFMA(a, bw, acc[t]);
            }
        }
        #pragma unroll
        for (int t = 0; t < 2; ++t) {
            int f = 16 * (wv + 8 * t) + c;
            float bias = fnb1[f];
            int kt2 = f >> 5, o8 = (f >> 3) & 3, j2 = f & 7;
            #pragma unroll
            for (int r = 0; r < 4; ++r) {
                float val = lrelu(acc[t][r] + bias);
                sH2p[((kt2) * 64 + (4 * Q + r) + 16 * o8) * 8 + j2] = f2bfu(val);
            }
        }
    }
    __syncthreads();

    // ---- node layer 2: K=256, N=32, linear -> out ----
    if (wv < 2) {
        int nt = wv;
        fx4 acc = (fx4){0.f, 0.f, 0.f, 0.f};
        for (int kt = 0; kt < 8; ++kt) {
            bf16x8 a = fragLds(sH2p + (kt * 64 + ld) * 8);
            bf16x8 bw = fragGbl(n2p + (size_t)((kt * 2 + nt) * 64 + ld) * 8);
            acc = MFMA(a, bw, acc);
        }
        int f = 16 * nt + c;
        float bias = fnb2[f];
        #pragma unroll
        for (int r = 0; r < 4; ++r) {
            int g = 16 * blk + 4 * Q + r;
            out[(size_t)g * FOUT + f] = acc[r] + bias;
        }
    }
}

extern "C" void kernel_launch(void* const* d_in, const int* in_sizes, int n_in,
                              void* d_out, int out_size, void* d_ws, size_t ws_size,
                              hipStream_t stream) {
    const float* x    = (const float*)d_in[0];
    const float* few0 = (const float*)d_in[1];
    const float* feb0 = (const float*)d_in[2];
    const float* few1 = (const float*)d_in[3];
    const float* feb1 = (const float*)d_in[4];
    const float* few2 = (const float*)d_in[5];
    const float* feb2 = (const float*)d_in[6];
    const float* fnw0 = (const float*)d_in[7];
    const float* fnb0 = (const float*)d_in[8];
    const float* fnw1 = (const float*)d_in[9];
    const float* fnb1 = (const float*)d_in[10];
    const float* fnw2 = (const float*)d_in[11];
    const float* fnb2 = (const float*)d_in[12];

    char* w = (char*)d_ws;
    float* P    = (float*)(w + OFF_P);
    float* V    = (float*)(w + OFF_V);
    u16*   agg  = (u16*)(w + OFF_AGG);
    u16*   pack = (u16*)(w + OFF_PACK);

    prep_kernel<<<PV_BLOCKS + PACK_BLOCKS, 512, 0, stream>>>(
        x, few0, feb0, few1, few2, fnw0, fnw1, fnw2, P, V, pack);

    edge_kernel<<<dim3(N_, B_), 512, 0, stream>>>(
        P, V, pack + PK_W1, pack + PK_W2, feb1, feb2, agg);

    node_kernel<<<400, 512, 0, stream>>>(
        agg, x, pack + PK_N0, pack + PK_N1, pack + PK_N2,
        fnb0, fnb1, fnb2, (float*)d_out);
}

// Round 5
// 228.946 us; speedup vs baseline: 2.9714x; 2.9714x over previous
//
#include <hip/hip_runtime.h>

#define B_    64
#define N_    100
#define D_    32
#define F0    96
#define F1    160
#define F2    192
#define HID   256
#define FOUT  32

typedef unsigned short u16;
typedef unsigned int   u32;
typedef u16   u16x8 __attribute__((ext_vector_type(8)));
typedef __bf16 bf16x8 __attribute__((ext_vector_type(8)));
typedef __bf16 bf16x2 __attribute__((ext_vector_type(2)));
typedef float  fx4   __attribute__((ext_vector_type(4)));

__device__ __forceinline__ u16 f2bfu(float f) {
    u32 u = __float_as_uint(f);
    u += 0x7fffu + ((u >> 16) & 1u);   // RNE
    return (u16)(u >> 16);
}
#if __has_builtin(__builtin_amdgcn_cvt_pk_bf16_f32)
__device__ __forceinline__ u32 pk2(float a, float b) {
    bf16x2 t = __builtin_amdgcn_cvt_pk_bf16_f32(a, b);
    return __builtin_bit_cast(u32, t);
}
#else
__device__ __forceinline__ u32 pk2(float a, float b) {
    return (u32)f2bfu(a) | ((u32)f2bfu(b) << 16);
}
#endif
__device__ __forceinline__ float lrelu(float v) { return fmaxf(v, 0.2f * v); }

__device__ __forceinline__ bf16x8 fragLds(const u16* p) {
    return __builtin_bit_cast(bf16x8, *(const u16x8*)p);
}
__device__ __forceinline__ bf16x8 fragGbl(const u16* __restrict__ p) {
    return __builtin_bit_cast(bf16x8, *(const u16x8*)p);
}
#define MFMA(a, b, c) __builtin_amdgcn_mfma_f32_16x16x32_bf16((a), (b), (c), 0, 0, 0)

// ---- ws layout (bytes) ----
#define OFF_P     0u
#define OFF_V     2457600u     // 6400*96*4
#define OFF_AGG   4915200u     // + 6400*96*4
#define OFF_PACK  7372800u     // + 6400*192*2
// packed weights (u16 element offsets); A-frag pack of W^T == B-frag pack of W
#define PK_W1     0            // 96x160  -> 15360
#define PK_W2     15360        // 160x192 -> 30720
#define PK_N0     46080        // 224x256 -> 57344
#define PK_N1     103424       // 256x256 -> 65536
#define PK_N2     168960       // 256x32  -> 8192
#define PK_TOTAL  177152

#define PV_BLOCKS 2400         // 6400*192 / 512
#define PACK_BLOCKS 346        // 177152 / 512

// ============================ prep ============================
__global__ __launch_bounds__(512) void prep_kernel(
    const float* __restrict__ x,
    const float* __restrict__ few0, const float* __restrict__ feb0,
    const float* __restrict__ few1, const float* __restrict__ few2,
    const float* __restrict__ fnw0, const float* __restrict__ fnw1,
    const float* __restrict__ fnw2,
    float* __restrict__ P, float* __restrict__ V, u16* __restrict__ wpack)
{
    const int blk = blockIdx.x, tid = threadIdx.x;
    if (blk < PV_BLOCKS) {
        int o = blk * 512 + tid;           // < 6400*192
        int r = o / 192, h = o - r * 192;
        const float* xr = x + r * D_;
        if (h < F0) {
            float acc = feb0[h];
            #pragma unroll
            for (int d = 0; d < D_; ++d) acc = fmaf(xr[d], few0[d * F0 + h], acc);
            P[r * F0 + h] = acc;
        } else {
            int k = h - F0;
            float acc = 0.f;
            #pragma unroll
            for (int d = 0; d < D_; ++d) acc = fmaf(xr[d], few0[(D_ + d) * F0 + k], acc);
            V[r * F0 + k] = acc;
        }
    } else {
        int p = (blk - PV_BLOCKS) * 512 + tid;   // < 177152
        const float* src; int start, Ncols, NT;
        if (p < PK_W2)      { start = PK_W1; src = few1; Ncols = F1;   NT = 10; }
        else if (p < PK_N0) { start = PK_W2; src = few2; Ncols = F2;   NT = 12; }
        else if (p < PK_N1) { start = PK_N0; src = fnw0; Ncols = HID;  NT = 16; }
        else if (p < PK_N2) { start = PK_N1; src = fnw1; Ncols = HID;  NT = 16; }
        else                { start = PK_N2; src = fnw2; Ncols = FOUT; NT = 2;  }
        int local = p - start;
        int j = local & 7, lane = (local >> 3) & 63, rest = local >> 9;
        int nt = rest % NT, kt = rest / NT;
        int n = 16 * nt + (lane & 15);
        int k = 32 * kt + 8 * (lane >> 4) + j;
        wpack[p] = f2bfu(src[k * Ncols + n]);
    }
}

// ============================ edge ============================
// one block per (b,i). Transposed MFMA: D = W^T (A-op) x Act^T (B-op).
// ALL register arrays indexed only by fully-unrolled compile-time loops
// (R4 regression: runtime trip counts -> scratch-allocated accumulators).
__global__ __launch_bounds__(512, 4) void edge_kernel(
    const float* __restrict__ P, const float* __restrict__ V,
    const u16* __restrict__ W1p, const u16* __restrict__ W2p,
    const float* __restrict__ feb1, const float* __restrict__ feb2,
    u16* __restrict__ agg)
{
    const int i = blockIdx.x, b = blockIdx.y;
    const int tid = threadIdx.x, ld = tid & 63, wv = tid >> 6;
    const int c = ld & 15, Q = ld >> 4;
    const int row = b * N_ + i;

    __shared__ __align__(16) u16  sB0[3 * 7 * 64 * 8];   // 21504 B: A0^T B-pack
    __shared__ __align__(16) u16  sB1[5 * 7 * 64 * 8];   // 35840 B: A1^T B-pack
    __shared__ __align__(16) float sP[F0];               //   384 B
    __shared__ __align__(16) float sAggP[2 * F2];        //  1536 B

    if (tid < 24) ((float4*)sP)[tid] = ((const float4*)(P + (size_t)row * F0))[tid];
    __syncthreads();

    // ---- build A0^T in B-pack layout (verified in R4) ----
    {
        const float* Vb = V + (size_t)b * (N_ * F0);
        #pragma unroll
        for (int s = 0; s < 3; ++s) {
            int o = tid + 512 * s;
            if (o < 1344) {
                int mt = o / 192;
                int rem = o - mt * 192;
                int kt = rem >> 6, lane = rem & 63;
                int m = 16 * mt + (lane & 15);
                int kb = 32 * kt + 8 * (lane >> 4);
                const float* vp = Vb + m * F0 + kb;   // pad rows: finite garbage, masked at agg
                float4 va = *(const float4*)vp;
                float4 vb = *(const float4*)(vp + 4);
                float4 pa = *(const float4*)&sP[kb];
                float4 pb = *(const float4*)&sP[kb + 4];
                uint4 w;
                w.x = pk2(lrelu(pa.x + va.x), lrelu(pa.y + va.y));
                w.y = pk2(lrelu(pa.z + va.z), lrelu(pa.w + va.w));
                w.z = pk2(lrelu(pb.x + vb.x), lrelu(pb.y + vb.y));
                w.w = pk2(lrelu(pb.z + vb.z), lrelu(pb.w + vb.w));
                *(uint4*)&sB0[o * 8] = w;
            }
        }
    }
    __syncthreads();

    // ---- layer 1 (transposed): wave = (wf: 5 f-tiles) x (wm: m-tiles wm, wm+4) ----
    {
        const int wf = wv >> 2, wm = wv & 3, ftb = wf * 5;
        #pragma unroll
        for (int mi = 0; mi < 2; ++mi) {
            const int mt = wm + 4 * mi;
            if (mt < 7) {                      // wave-uniform guard
                bf16x8 b0[3];
                #pragma unroll
                for (int kt = 0; kt < 3; ++kt)
                    b0[kt] = fragLds(sB0 + ((mt * 3 + kt) * 64 + ld) * 8);
                #pragma unroll
                for (int t = 0; t < 5; ++t) {
                    const int ft = ftb + t;
                    fx4 acc = (fx4){0.f, 0.f, 0.f, 0.f};
                    #pragma unroll
                    for (int kt = 0; kt < 3; ++kt) {
                        bf16x8 aw = fragGbl(W1p + (size_t)((kt * 10 + ft) * 64 + ld) * 8);
                        acc = MFMA(aw, b0[kt], acc);
                    }
                    // rows f = 16*ft + 4Q + r ; cols m = 16mt + c -> packed uint2 store
                    const int f0 = 16 * ft + 4 * Q;
                    float4 bias = *(const float4*)(feb1 + f0);
                    u32 lo = pk2(lrelu(acc[0] + bias.x), lrelu(acc[1] + bias.y));
                    u32 hi = pk2(lrelu(acc[2] + bias.z), lrelu(acc[3] + bias.w));
                    const int kt2 = f0 >> 5, o8 = (f0 >> 3) & 3, j0 = f0 & 7;
                    *(uint2*)&sB1[((mt * 5 + kt2) * 64 + c + 16 * o8) * 8 + j0] = (uint2){lo, hi};
                }
            }
        }
    }
    __syncthreads();

    // ---- layer 2 (transposed) + fused aggregation over m ----
    {
        const int wf2 = wv >> 1, wm2 = wv & 1;
        float ag[3][4];
        #pragma unroll
        for (int t = 0; t < 3; ++t)
            #pragma unroll
            for (int r = 0; r < 4; ++r) ag[t][r] = 0.f;

        #pragma unroll
        for (int mi = 0; mi < 4; ++mi) {
            const int mt = wm2 + 2 * mi;
            if (mt < 7) {                      // wave-uniform guard
                bf16x8 b1[5];
                #pragma unroll
                for (int kt = 0; kt < 5; ++kt)
                    b1[kt] = fragLds(sB1 + ((mt * 5 + kt) * 64 + ld) * 8);
                #pragma unroll
                for (int t = 0; t < 3; ++t) {
                    const int ft = wf2 + 4 * t;
                    fx4 acc = (fx4){0.f, 0.f, 0.f, 0.f};
                    #pragma unroll
                    for (int kt = 0; kt < 5; ++kt) {
                        bf16x8 aw = fragGbl(W2p + (size_t)((kt * 12 + ft) * 64 + ld) * 8);
                        acc = MFMA(aw, b1[kt], acc);
                    }
                    const int f0 = 16 * ft + 4 * Q;
                    float4 bias = *(const float4*)(feb2 + f0);
                    const bool pad = (mt == 6) && (c >= 4);   // m = 16*6 + c >= 100
                    ag[t][0] += pad ? 0.f : lrelu(acc[0] + bias.x);
                    ag[t][1] += pad ? 0.f : lrelu(acc[1] + bias.y);
                    ag[t][2] += pad ? 0.f : lrelu(acc[2] + bias.z);
                    ag[t][3] += pad ? 0.f : lrelu(acc[3] + bias.w);
                }
            }
        }
        // reduce over the 16 m-lanes (c)
        #pragma unroll
        for (int t = 0; t < 3; ++t)
            #pragma unroll
            for (int r = 0; r < 4; ++r) {
                float v = ag[t][r];
                v += __shfl_xor(v, 1);
                v += __shfl_xor(v, 2);
                v += __shfl_xor(v, 4);
                v += __shfl_xor(v, 8);
                ag[t][r] = v;
            }
        if (c == 0) {
            #pragma unroll
            for (int t = 0; t < 3; ++t) {
                float4 vv = {ag[t][0], ag[t][1], ag[t][2], ag[t][3]};
                *(float4*)&sAggP[wm2 * F2 + 16 * (wf2 + 4 * t) + 4 * Q] = vv;
            }
        }
    }
    __syncthreads();

    if (tid < F2)
        agg[(size_t)row * F2 + tid] = f2bfu(sAggP[tid] + sAggP[F2 + tid]);
}

// ============================ node ============================
// 400 blocks x 16 rows, 512 threads (8 waves = 8 n-groups)
__global__ __launch_bounds__(512, 4) void node_kernel(
    const u16* __restrict__ agg, const float* __restrict__ x,
    const u16* __restrict__ n0p, const u16* __restrict__ n1p,
    const u16* __restrict__ n2p,
    const float* __restrict__ fnb0, const float* __restrict__ fnb1,
    const float* __restrict__ fnb2,
    float* __restrict__ out)
{
    const int blk = blockIdx.x;
    const int tid = threadIdx.x, ld = tid & 63, wv = tid >> 6;
    const int c = ld & 15, Q = ld >> 4;

    __shared__ __align__(16) u16 sH0p[7 * 512];   //  7168 B
    __shared__ __align__(16) u16 sH1p[8 * 512];   //  8192 B
    __shared__ __align__(16) u16 sH2p[8 * 512];   //  8192 B

    // ---- stage H0 = [agg | x] in A-pack layout (16 rows) ----
    if (tid < 448) {
        int kt = tid >> 6, lane = tid & 63;
        int m = lane & 15;
        int kb = 32 * kt + 8 * (lane >> 4);
        int g = 16 * blk + m;
        uint4 w;
        if (kb < F2) {
            w = *(const uint4*)(agg + (size_t)g * F2 + kb);
        } else {
            const float* xp = x + (size_t)g * D_ + (kb - F2);
            float4 a = *(const float4*)xp;
            float4 bb = *(const float4*)(xp + 4);
            w.x = pk2(a.x, a.y);  w.y = pk2(a.z, a.w);
            w.z = pk2(bb.x, bb.y); w.w = pk2(bb.z, bb.w);
        }
        *(uint4*)&sH0p[tid * 8] = w;
    }
    __syncthreads();

    // ---- node layer 0: K=224, N=256 ; wave handles nt = wv, wv+8 ----
    {
        fx4 acc[2];
        #pragma unroll
        for (int t = 0; t < 2; ++t) acc[t] = (fx4){0.f, 0.f, 0.f, 0.f};
        for (int kt = 0; kt < 7; ++kt) {
            bf16x8 a = fragLds(sH0p + (kt * 64 + ld) * 8);
            #pragma unroll
            for (int t = 0; t < 2; ++t) {
                bf16x8 bw = fragGbl(n0p + (size_t)((kt * 16 + wv + 8 * t) * 64 + ld) * 8);
                acc[t] = MFMA(a, bw, acc[t]);
            }
        }
        #pragma unroll
        for (int t = 0; t < 2; ++t) {
            int f = 16 * (wv + 8 * t) + c;
            float bias = fnb0[f];
            int kt2 = f >> 5, o8 = (f >> 3) & 3, j2 = f & 7;
            #pragma unroll
            for (int r = 0; r < 4; ++r) {
                float val = lrelu(acc[t][r] + bias);
                sH1p[((kt2) * 64 + (4 * Q + r) + 16 * o8) * 8 + j2] = f2bfu(val);
            }
        }
    }
    __syncthreads();

    // ---- node layer 1: K=256, N=256 ----
    {
        fx4 acc[2];
        #pragma unroll
        for (int t = 0; t < 2; ++t) acc[t] = (fx4){0.f, 0.f, 0.f, 0.f};
        for (int kt = 0; kt < 8; ++kt) {
            bf16x8 a = fragLds(sH1p + (kt * 64 + ld) * 8);
            #pragma unroll
            for (int t = 0; t < 2; ++t) {
                bf16x8 bw = fragGbl(n1p + (size_t)((kt * 16 + wv + 8 * t) * 64 + ld) * 8);
                acc[t] = MFMA(a, bw, acc[t]);
            }
        }
        #pragma unroll
        for (int t = 0; t < 2; ++t) {
            int f = 16 * (wv + 8 * t) + c;
            float bias = fnb1[f];
            int kt2 = f >> 5, o8 = (f >> 3) & 3, j2 = f & 7;
            #pragma unroll
            for (int r = 0; r < 4; ++r) {
                float val = lrelu(acc[t][r] + bias);
                sH2p[((kt2) * 64 + (4 * Q + r) + 16 * o8) * 8 + j2] = f2bfu(val);
            }
        }
    }
    __syncthreads();

    // ---- node layer 2: K=256, N=32, linear -> out ----
    if (wv < 2) {
        int nt = wv;
        fx4 acc = (fx4){0.f, 0.f, 0.f, 0.f};
        for (int kt = 0; kt < 8; ++kt) {
            bf16x8 a = fragLds(sH2p + (kt * 64 + ld) * 8);
            bf16x8 bw = fragGbl(n2p + (size_t)((kt * 2 + nt) * 64 + ld) * 8);
            acc = MFMA(a, bw, acc);
        }
        int f = 16 * nt + c;
        float bias = fnb2[f];
        #pragma unroll
        for (int r = 0; r < 4; ++r) {
            int g = 16 * blk + 4 * Q + r;
            out[(size_t)g * FOUT + f] = acc[r] + bias;
        }
    }
}

extern "C" void kernel_launch(void* const* d_in, const int* in_sizes, int n_in,
                              void* d_out, int out_size, void* d_ws, size_t ws_size,
                              hipStream_t stream) {
    const float* x    = (const float*)d_in[0];
    const float* few0 = (const float*)d_in[1];
    const float* feb0 = (const float*)d_in[2];
    const float* few1 = (const float*)d_in[3];
    const float* feb1 = (const float*)d_in[4];
    const float* few2 = (const float*)d_in[5];
    const float* feb2 = (const float*)d_in[6];
    const float* fnw0 = (const float*)d_in[7];
    const float* fnb0 = (const float*)d_in[8];
    const float* fnw1 = (const float*)d_in[9];
    const float* fnb1 = (const float*)d_in[10];
    const float* fnw2 = (const float*)d_in[11];
    const float* fnb2 = (const float*)d_in[12];

    char* w = (char*)d_ws;
    float* P    = (float*)(w + OFF_P);
    float* V    = (float*)(w + OFF_V);
    u16*   agg  = (u16*)(w + OFF_AGG);
    u16*   pack = (u16*)(w + OFF_PACK);

    prep_kernel<<<PV_BLOCKS + PACK_BLOCKS, 512, 0, stream>>>(
        x, few0, feb0, few1, few2, fnw0, fnw1, fnw2, P, V, pack);

    edge_kernel<<<dim3(N_, B_), 512, 0, stream>>>(
        P, V, pack + PK_W1, pack + PK_W2, feb1, feb2, agg);

    node_kernel<<<400, 512, 0, stream>>>(
        agg, x, pack + PK_N0, pack + PK_N1, pack + PK_N2,
        fnb0, fnb1, fnb2, (float*)d_out);
}